// Round 1
// baseline (325.938 us; speedup 1.0000x reference)
//
#include <hip/hip_runtime.h>
#include <math.h>

#define B_ROWS 131072
#define DDIM 256
#define EPSF 1e-7f
#define NB1 2048   // blocks for k_main; must divide B_ROWS/4
#define NB3 512    // blocks for k_rloss; NB3*256 == B_ROWS

// ---------- ws layout (bytes) ----------
#define WP_OFF   0         // float[8*256]
#define SP_OFF   8192      // float[8*256]
#define Z0_OFF   16384     // float[8*256]
#define SCAL_OFF 24576     // float[32]: [0..7]=b, [8..15]=wdots, [16..23]=a, [24..31]=beta
#define PBSS_OFF 24832     // double[8][NB1]
#define PBPL_OFF 155904    // double[NB1]
#define RV_OFF   172288    // double[8]
#define PL_OFF   172352    // double[1]
#define PBRL_OFF 172416    // double[NB3]
#define HW_OFF   176640    // float[8][B_ROWS]

__device__ __forceinline__ float waveReduceSum(float v) {
#pragma unroll
    for (int m = 32; m > 0; m >>= 1) v += __shfl_xor(v, m, 64);
    return v;
}

__device__ __forceinline__ float blockReduce256f(float v, float* sred) {
    int t = threadIdx.x;
    sred[t] = v;
    __syncthreads();
#pragma unroll
    for (int off = 128; off > 0; off >>= 1) {
        if (t < off) sred[t] += sred[t + off];
        __syncthreads();
    }
    float r = sred[0];
    __syncthreads();
    return r;
}

__device__ __forceinline__ double blockReduce256d(double v, double* sred) {
    int t = threadIdx.x;
    sred[t] = v;
    __syncthreads();
#pragma unroll
    for (int off = 128; off > 0; off >>= 1) {
        if (t < off) sred[t] += sred[t + off];
        __syncthreads();
    }
    double r = sred[0];
    __syncthreads();
    return r;
}

// ---------------- k0: parameter corrections + packing ----------------
__global__ __launch_bounds__(256) void k_params(
    const float* __restrict__ pw, const float* __restrict__ pb,
    const float* __restrict__ ps, const float* __restrict__ rz0,
    const float* __restrict__ ra, const float* __restrict__ rb,
    float* __restrict__ wp, float* __restrict__ sp,
    float* __restrict__ z0w, float* __restrict__ scal)
{
    __shared__ float sred[256];
    int d = threadIdx.x;
    for (int p = 0; p < 8; ++p) {
        int i = 2 * p;          // planar layer index (even)
        int ir = i + 1;         // radial layer index (odd)
        float w = pw[i * DDIM + d];
        float s = ps[i * DDIM + d];
        float margin = blockReduce256f(w * s, sred);
        float wn2 = blockReduce256f(w * w, sred);
        float s_corr = s;
        if (margin < -1.0f) {
            float comp = -1.0f + log1pf(expf(margin)) - margin;
            s_corr = s + comp * w / sqrtf(wn2);
        }
        wp[p * DDIM + d] = w;
        sp[p * DDIM + d] = s_corr;
        float wdots = blockReduce256f(w * s_corr, sred);
        z0w[p * DDIM + d] = rz0[ir * DDIM + d];
        if (d == 0) {
            scal[p]      = pb[i];
            scal[8 + p]  = wdots;
            float a = ra[ir];
            float beta = rb[ir];
            if (beta < -a) beta = -a + log1pf(expf(beta));
            scal[16 + p] = a;
            scal[24 + p] = beta;
        }
        __syncthreads();
    }
}

// ---------------- k1: main per-row chain ----------------
__global__ __launch_bounds__(256) void k_main(
    const float* __restrict__ z_in, float* __restrict__ z_out,
    const float* __restrict__ wp, const float* __restrict__ sp,
    const float* __restrict__ z0w, const float* __restrict__ scal,
    float* __restrict__ h_ws, double* __restrict__ pb_ss,
    double* __restrict__ pb_pl)
{
    __shared__ float swp[8 * DDIM];
    __shared__ float ssp[8 * DDIM];
    __shared__ float sz0[8 * DDIM];
    __shared__ double sred[4];

    for (int idx = threadIdx.x; idx < 8 * DDIM; idx += 256) {
        swp[idx] = wp[idx];
        ssp[idx] = sp[idx];
        sz0[idx] = z0w[idx];
    }
    float pbv[8], wds[8], av[8], bv[8];
#pragma unroll
    for (int p = 0; p < 8; ++p) {
        pbv[p] = scal[p];
        wds[p] = scal[8 + p];
        av[p]  = scal[16 + p];
        bv[p]  = scal[24 + p];
    }
    __syncthreads();

    int wid = threadIdx.x >> 6;
    int lane = threadIdx.x & 63;
    double acc_ss[8];
#pragma unroll
    for (int q = 0; q < 8; ++q) acc_ss[q] = 0.0;
    double acc_pl = 0.0;

    const int G = B_ROWS / 4;
    for (int g = blockIdx.x; g < G; g += gridDim.x) {
        int row = g * 4 + wid;
        float4 zv = ((const float4*)(z_in + (size_t)row * DDIM))[lane];
#pragma unroll
        for (int i = 0; i < 16; ++i) {
            if ((i & 1) == 0) {               // planar
                int p = i >> 1;
                float4 wv = ((const float4*)(swp + p * DDIM))[lane];
                float t = zv.x * wv.x + zv.y * wv.y + zv.z * wv.z + zv.w * wv.w;
                t = waveReduceSum(t);
                float act = tanhf(t + pbv[p]);
                float4 sv = ((const float4*)(ssp + p * DDIM))[lane];
                zv.x += sv.x * act; zv.y += sv.y * act;
                zv.z += sv.z * act; zv.w += sv.w * act;
                float det = 1.0f + (1.0f - act * act) * wds[p];
                float ll = logf(fabsf(det) + EPSF);
                if (lane == 0) acc_pl += (double)ll;
            } else {                           // radial
                int r = i >> 1;
                float4 z0v = ((const float4*)(sz0 + r * DDIM))[lane];
                float4 rd;
                rd.x = zv.x - z0v.x; rd.y = zv.y - z0v.y;
                rd.z = zv.z - z0v.z; rd.w = zv.w - z0v.w;
                float t = rd.x * rd.x + rd.y * rd.y + rd.z * rd.z + rd.w * rd.w;
                float r2 = waveReduceSum(t);
                float rr = sqrtf(r2);
                float h = 1.0f / (av[r] + rr);
                float bh = bv[r] * h;
                zv.x += bh * rd.x; zv.y += bh * rd.y;
                zv.z += bh * rd.z; zv.w += bh * rd.w;
                if (lane == 0) {
                    h_ws[(size_t)r * B_ROWS + row] = h;
                    acc_ss[r] += (double)r2;
                }
            }
        }
        ((float4*)(z_out + (size_t)row * DDIM))[lane] = zv;
    }

    // deterministic per-block partials (9 quantities)
    __syncthreads();
#pragma unroll
    for (int q = 0; q < 9; ++q) {
        double v = (q < 8) ? acc_ss[q] : acc_pl;
        if (lane == 0) sred[wid] = v;
        __syncthreads();
        if (threadIdx.x == 0) {
            double t = sred[0] + sred[1] + sred[2] + sred[3];
            if (q < 8) pb_ss[q * NB1 + blockIdx.x] = t;
            else       pb_pl[blockIdx.x] = t;
        }
        __syncthreads();
    }
}

// ---------------- k2: reduce partials -> R[8], planar loss total ----------------
__global__ __launch_bounds__(256) void k_stats(
    const double* __restrict__ pb_ss, const double* __restrict__ pb_pl,
    double* __restrict__ Rv, double* __restrict__ PL)
{
    __shared__ double sd[256];
    int t = threadIdx.x;
    for (int q = 0; q < 9; ++q) {
        double v = 0.0;
        if (q < 8) { for (int j = t; j < NB1; j += 256) v += pb_ss[q * NB1 + j]; }
        else       { for (int j = t; j < NB1; j += 256) v += pb_pl[j]; }
        double tot = blockReduce256d(v, sd);
        if (t == 0) {
            if (q < 8) Rv[q] = sqrt(tot);
            else       PL[0] = tot;
        }
        __syncthreads();
    }
}

// ---------------- k3: radial loss (needs global R) ----------------
__global__ __launch_bounds__(256) void k_rloss(
    const float* __restrict__ h_ws, const float* __restrict__ scal,
    const double* __restrict__ Rv, double* __restrict__ pb_rl)
{
    __shared__ double sd[256];
    int row = blockIdx.x * 256 + threadIdx.x;
    double ls = 0.0;
#pragma unroll
    for (int r = 0; r < 8; ++r) {
        double h = (double)h_ws[(size_t)r * B_ROWS + row];
        double beta = (double)scal[24 + r];
        double bh = beta * h;
        double t1 = 1.0 + bh;
        double diag = pow(t1, 255.0);
        double det = diag * (t1 - beta * h * h * Rv[r]);
        ls += log(fabs(det) + 1e-7);
    }
    double tot = blockReduce256d(ls, sd);
    if (threadIdx.x == 0) pb_rl[blockIdx.x] = tot;
}

// ---------------- k4: final combine ----------------
__global__ __launch_bounds__(256) void k_final(
    const double* __restrict__ pb_rl, const double* __restrict__ PL,
    float* __restrict__ out_loss)
{
    __shared__ double sd[256];
    int t = threadIdx.x;
    double v = 0.0;
    for (int j = t; j < NB3; j += 256) v += pb_rl[j];
    double tot = blockReduce256d(v, sd);
    if (t == 0) out_loss[0] = (float)((tot + PL[0]) / (double)B_ROWS);
}

extern "C" void kernel_launch(void* const* d_in, const int* in_sizes, int n_in,
                              void* d_out, int out_size, void* d_ws, size_t ws_size,
                              hipStream_t stream) {
    const float* z   = (const float*)d_in[0];
    const float* pw  = (const float*)d_in[1];
    const float* pb  = (const float*)d_in[2];
    const float* ps  = (const float*)d_in[3];
    const float* rz0 = (const float*)d_in[4];
    const float* ra  = (const float*)d_in[5];
    const float* rb  = (const float*)d_in[6];
    float* out = (float*)d_out;

    char* ws = (char*)d_ws;
    float*  wp    = (float*)(ws + WP_OFF);
    float*  sp    = (float*)(ws + SP_OFF);
    float*  z0w   = (float*)(ws + Z0_OFF);
    float*  scal  = (float*)(ws + SCAL_OFF);
    double* pb_ss = (double*)(ws + PBSS_OFF);
    double* pb_pl = (double*)(ws + PBPL_OFF);
    double* Rv    = (double*)(ws + RV_OFF);
    double* PL    = (double*)(ws + PL_OFF);
    double* pb_rl = (double*)(ws + PBRL_OFF);
    float*  h_ws  = (float*)(ws + HW_OFF);

    k_params<<<1, 256, 0, stream>>>(pw, pb, ps, rz0, ra, rb, wp, sp, z0w, scal);
    k_main<<<NB1, 256, 0, stream>>>(z, out, wp, sp, z0w, scal, h_ws, pb_ss, pb_pl);
    k_stats<<<1, 256, 0, stream>>>(pb_ss, pb_pl, Rv, PL);
    k_rloss<<<NB3, 256, 0, stream>>>(h_ws, scal, Rv, pb_rl);
    k_final<<<1, 256, 0, stream>>>(pb_rl, PL, out + (size_t)B_ROWS * DDIM);
}